// Round 4
// baseline (165.645 us; speedup 1.0000x reference)
//
#include <hip/hip_runtime.h>
#include <math.h>

#define N_VEC 65536
#define D 64
#define K 1024
#define VQ_EPS 1e-10f

typedef __attribute__((ext_vector_type(8))) short s16x8;   // 8 bf16 = 4 VGPR
typedef __attribute__((ext_vector_type(4))) float f32x4;   // MFMA acc

#define MFMA(a, b, c) __builtin_amdgcn_mfma_f32_16x16x32_bf16((a), (b), (c), 0, 0, 0)

__device__ __forceinline__ unsigned short bf16_rne(float f) {
    unsigned u = __float_as_uint(f);
    u += 0x7fff + ((u >> 16) & 1);
    return (unsigned short)(u >> 16);
}
__device__ __forceinline__ float bf16_f32(unsigned short h) {
    return __uint_as_float(((unsigned)h) << 16);
}

// async global->LDS DMA, 16 B per lane; LDS dest = wave-uniform base + lane*16
__device__ __forceinline__ void async_load16(const void* g, void* lds_generic) {
    __builtin_amdgcn_global_load_lds(
        (const __attribute__((address_space(1))) unsigned int*)g,
        (__attribute__((address_space(3))) unsigned int*)lds_generic, 16, 0, 0);
}

// ---------------------------------------------------------------------------
// Kernel A: pack embeddings into MFMA-fragment order (verified layout).
// Chunk id = ct*16 + g*4 + bg (bg: 0=hi k0-31, 1=hi k32-63, 2=lo k0-31,
// 3=lo k32-63). Slot q*16+c in a chunk = 16 B = 8 bf16 of code g*16+c.
// enorm stores -0.5*||e||^2; counts[K] doubles as completion counter.
// ---------------------------------------------------------------------------
__global__ void pack_e_kernel(const float* __restrict__ emb,
                              uint4* __restrict__ ep4,
                              float* __restrict__ enorm,
                              int* __restrict__ counts) {
    int gid = blockIdx.x * 64 + threadIdx.x;       // 0..4095
    int code = gid >> 2, tq = gid & 3;             // tq: k-quarter (16 elems)
    const float* row = emb + (size_t)code * D + tq * 16;
    unsigned int hi[8], lo[8];
    float nrm = 0.f;
#pragma unroll
    for (int i = 0; i < 4; ++i) {
        float4 v = *reinterpret_cast<const float4*>(row + i * 4);
        nrm += v.x * v.x + v.y * v.y + v.z * v.z + v.w * v.w;
        float f[4] = {v.x, v.y, v.z, v.w};
        unsigned short hh[4], ll[4];
#pragma unroll
        for (int j = 0; j < 4; ++j) {
            hh[j] = bf16_rne(f[j]);
            ll[j] = bf16_rne(f[j] - bf16_f32(hh[j]));
        }
        hi[i * 2 + 0] = (unsigned)hh[0] | ((unsigned)hh[1] << 16);
        hi[i * 2 + 1] = (unsigned)hh[2] | ((unsigned)hh[3] << 16);
        lo[i * 2 + 0] = (unsigned)ll[0] | ((unsigned)ll[1] << 16);
        lo[i * 2 + 1] = (unsigned)ll[2] | ((unsigned)ll[3] << 16);
    }
    const int ct = code >> 6, g = (code >> 4) & 3, c = code & 15;
#pragma unroll
    for (int h = 0; h < 2; ++h) {
        int gran = 2 * tq + h;               // 0..7
        int bg = gran >> 2, qq = gran & 3;
        ep4[(size_t)(ct * 16 + g * 4 + bg) * 64 + qq * 16 + c] =
            make_uint4(hi[h * 4], hi[h * 4 + 1], hi[h * 4 + 2], hi[h * 4 + 3]);
        int granl = 8 + gran;                // lo: bg 2..3
        bg = granl >> 2; qq = granl & 3;
        ep4[(size_t)(ct * 16 + g * 4 + bg) * 64 + qq * 16 + c] =
            make_uint4(lo[h * 4], lo[h * 4 + 1], lo[h * 4 + 2], lo[h * 4 + 3]);
    }
    nrm += __shfl_xor(nrm, 1, 64);
    nrm += __shfl_xor(nrm, 2, 64);
    if (tq == 0) enorm[code] = -0.5f * nrm;        // pre-negated half-norm
    if (gid <= K) counts[gid] = 0;                 // counts[K] = completion ctr
}

// ---------------------------------------------------------------------------
// Kernel B: R0 shell (measured-best: 4 blocks/CU, 16 waves/CU, 16 KB dbuf
// tiles, barrier per tile) + ONE structural change: BATCHED ARGMAX.
// Cross-round evidence (R0-R3): per-wave cost ~2.5-4K cyc per 16-code group
// regardless of barriers/B-source/chain interleave => the per-group
// MFMA->VALU consume + VALU->MFMA C-init round-trip is the stall.
// Fix: all 24 MFMAs of a tile (4 groups x 6-chain, pairwise-interleaved,
// C-init = shared zero reg) issue as one uninterrupted stretch; ONE batched
// best-update per tile reads acc[4] in issue order, adding -||e||^2/2 then.
//  - score = dot - enc/2; argmax score == argmin dist; strict >, ascending
//    scan = first-occurrence ties. C-layout: col=lane&15, row=(lane>>4)*4+reg.
// ---------------------------------------------------------------------------
__global__ void __launch_bounds__(256, 4)
vq_kernel(const float* __restrict__ x,
          const float* __restrict__ emb,
          const uint4* __restrict__ ep4,
          const float* __restrict__ enormp,   // holds -0.5*||e||^2
          int* __restrict__ counts,           // K+1 ints; [K] = completion ctr
          float* __restrict__ out) {
    __shared__ __align__(16) unsigned short bt[2][64 * 128];   // 2 x 16 KB B
    __shared__ __align__(16) float en[K];                      // 4 KB norms
    __shared__ int   bks[64];
    __shared__ float ws[4];
    __shared__ int   amLast;

    const int t    = threadIdx.x;
    const int w    = t >> 6;
    const int lane = t & 63;
    const int q    = lane >> 4;
    const int c    = lane & 15;
    const int vb   = blockIdx.x * 64;

    // ---- all 1024 norms -> LDS (one float4 per thread) ----
    reinterpret_cast<float4*>(en)[t] = reinterpret_cast<const float4*>(enormp)[t];

    // ---- A-frags: 16 vectors/wave, bf16 hi/lo (16 VGPR) ----
    s16x8 Ah0, Ah1, Al0, Al1;
#define LOAD_A(h, AH, AL)                                                      \
    {                                                                          \
        const float* xr = x + (size_t)(vb + w * 16 + c) * D + (h) * 32 + q * 8;\
        float4 u0 = *reinterpret_cast<const float4*>(xr);                      \
        float4 u1 = *reinterpret_cast<const float4*>(xr + 4);                  \
        float f[8] = {u0.x, u0.y, u0.z, u0.w, u1.x, u1.y, u1.z, u1.w};         \
        s16x8 hiv, lov;                                                        \
        _Pragma("unroll") for (int j = 0; j < 8; ++j) {                        \
            unsigned short hb = bf16_rne(f[j]);                                \
            hiv[j] = (short)hb;                                                \
            lov[j] = (short)bf16_rne(f[j] - bf16_f32(hb));                     \
        }                                                                      \
        AH = hiv; AL = lov;                                                    \
    }
    LOAD_A(0, Ah0, Al0)
    LOAD_A(1, Ah1, Al1)
#undef LOAD_A

    // ---- prologue: DMA tile 0's chunks (wave w -> chunks w*4..w*4+3) ----
    {
        const char* gbase = (const char*)ep4 + (size_t)(w * 4) * 1024 + lane * 16;
        char* lbase = (char*)bt[0] + (w * 4) * 1024;
#pragma unroll
        for (int i = 0; i < 4; ++i)
            async_load16(gbase + i * 1024, lbase + i * 1024);
    }

    float best[4];
    int   bk_[4];
#pragma unroll
    for (int s = 0; s < 4; ++s) { best[s] = -3.4e38f; bk_[s] = 0; }

    const f32x4 zf = (f32x4){0.f, 0.f, 0.f, 0.f};   // shared zero C operand

#pragma unroll 1
    for (int ct = 0; ct < 16; ++ct) {
        __syncthreads();   // vmcnt(0)+barrier: tile ct ready in bt[ct&1];
                           // everyone done reading bt[(ct+1)&1]

        if (ct < 15) {     // DMA next tile into the other buffer
            const char* gbase = (const char*)ep4
                + (size_t)((ct + 1) * 16 + w * 4) * 1024 + lane * 16;
            char* lbase = (char*)bt[(ct + 1) & 1] + (w * 4) * 1024;
#pragma unroll
            for (int i = 0; i < 4; ++i)
                async_load16(gbase + i * 1024, lbase + i * 1024);
        }

        const unsigned short* bufS = bt[ct & 1];

        // per-group -||e||^2/2 biases (added in the batched update pass)
        float e2v[4];
#pragma unroll
        for (int g = 0; g < 4; ++g) e2v[g] = en[ct * 64 + g * 16 + c];

        f32x4 acc0, acc1, acc2, acc3;

        // ---- pair 0: groups 0,1 — 12 MFMAs, two interleaved 6-chains ----
        {
            const unsigned short* b0 = bufS + 0 * 2048 + lane * 8;
            const unsigned short* b1 = bufS + 1 * 2048 + lane * 8;
            s16x8 B00 = *reinterpret_cast<const s16x8*>(b0);
            s16x8 B01 = *reinterpret_cast<const s16x8*>(b0 + 512);
            s16x8 B02 = *reinterpret_cast<const s16x8*>(b0 + 1024);
            s16x8 B03 = *reinterpret_cast<const s16x8*>(b0 + 1536);
            s16x8 B10 = *reinterpret_cast<const s16x8*>(b1);
            s16x8 B11 = *reinterpret_cast<const s16x8*>(b1 + 512);
            s16x8 B12 = *reinterpret_cast<const s16x8*>(b1 + 1024);
            s16x8 B13 = *reinterpret_cast<const s16x8*>(b1 + 1536);
            acc0 = MFMA(Ah0, B00, zf);   acc1 = MFMA(Ah0, B10, zf);
            acc0 = MFMA(Ah1, B01, acc0); acc1 = MFMA(Ah1, B11, acc1);
            acc0 = MFMA(Ah0, B02, acc0); acc1 = MFMA(Ah0, B12, acc1);
            acc0 = MFMA(Ah1, B03, acc0); acc1 = MFMA(Ah1, B13, acc1);
            acc0 = MFMA(Al0, B00, acc0); acc1 = MFMA(Al0, B10, acc1);
            acc0 = MFMA(Al1, B01, acc0); acc1 = MFMA(Al1, B11, acc1);
        }
        // ---- pair 1: groups 2,3 ----
        {
            const unsigned short* b2 = bufS + 2 * 2048 + lane * 8;
            const unsigned short* b3 = bufS + 3 * 2048 + lane * 8;
            s16x8 B20 = *reinterpret_cast<const s16x8*>(b2);
            s16x8 B21 = *reinterpret_cast<const s16x8*>(b2 + 512);
            s16x8 B22 = *reinterpret_cast<const s16x8*>(b2 + 1024);
            s16x8 B23 = *reinterpret_cast<const s16x8*>(b2 + 1536);
            s16x8 B30 = *reinterpret_cast<const s16x8*>(b3);
            s16x8 B31 = *reinterpret_cast<const s16x8*>(b3 + 512);
            s16x8 B32 = *reinterpret_cast<const s16x8*>(b3 + 1024);
            s16x8 B33 = *reinterpret_cast<const s16x8*>(b3 + 1536);
            acc2 = MFMA(Ah0, B20, zf);   acc3 = MFMA(Ah0, B30, zf);
            acc2 = MFMA(Ah1, B21, acc2); acc3 = MFMA(Ah1, B31, acc3);
            acc2 = MFMA(Ah0, B22, acc2); acc3 = MFMA(Ah0, B32, acc3);
            acc2 = MFMA(Ah1, B23, acc2); acc3 = MFMA(Ah1, B33, acc3);
            acc2 = MFMA(Al0, B20, acc2); acc3 = MFMA(Al0, B30, acc3);
            acc2 = MFMA(Al1, B21, acc2); acc3 = MFMA(Al1, B31, acc3);
        }

        // ---- batched update: one MFMA->VALU consume per TILE, issue order --
#define UPD(ACC, G)                                                            \
        {                                                                      \
            const int codeG = ct * 64 + (G) * 16 + c;                          \
            _Pragma("unroll")                                                  \
            for (int r = 0; r < 4; ++r) {                                      \
                float v = ACC[r] + e2v[G];                                     \
                if (v > best[r]) { best[r] = v; bk_[r] = codeG; }              \
            }                                                                  \
        }
        UPD(acc0, 0) UPD(acc1, 1) UPD(acc2, 2) UPD(acc3, 3)
#undef UPD
    }

    // ---- reduce over the 16 code-columns (max score; tie -> smaller idx) ----
#pragma unroll
    for (int m = 1; m <= 8; m <<= 1)
#pragma unroll
        for (int s = 0; s < 4; ++s) {
            float ob = __shfl_xor(best[s], m, 64);
            int   ok = __shfl_xor(bk_[s], m, 64);
            if (ob > best[s] || (ob == best[s] && ok < bk_[s])) {
                best[s] = ob; bk_[s] = ok;
            }
        }
    if (c == 0) {
#pragma unroll
        for (int r = 0; r < 4; ++r) {
            int lv = w * 16 + q * 4 + r;
            int kk = bk_[r];
            bks[lv] = kk;
            atomicAdd(&counts[kk], 1);
        }
    }
    __syncthreads();

    // ---- gather winning rows -> out (exact fp32) ----
    {
        int vec = t >> 2, part = t & 3;
        int kk = bks[vec];
        const float4* src = reinterpret_cast<const float4*>(emb + (size_t)kk * D) + part * 4;
        float4* dst = reinterpret_cast<float4*>(out + (size_t)(vb + vec) * D) + part * 4;
#pragma unroll
        for (int j = 0; j < 4; ++j) dst[j] = src[j];
    }

    // ---- last finishing block computes perplexity from counts ----
    __syncthreads();
    if (t == 0) {
        __threadfence();
        amLast = (atomicAdd(&counts[K], 1) == (int)gridDim.x - 1);
    }
    __syncthreads();
    if (amLast) {
        float s = 0.f;
#pragma unroll
        for (int i = 0; i < 4; ++i) {
            int cnt = __hip_atomic_load(&counts[t + i * 256], __ATOMIC_RELAXED,
                                        __HIP_MEMORY_SCOPE_AGENT);
            float p = (float)cnt * (1.0f / (float)N_VEC);
            s += p * logf(p + VQ_EPS);
        }
#pragma unroll
        for (int m = 1; m < 64; m <<= 1) s += __shfl_xor(s, m, 64);
        if (lane == 0) ws[w] = s;
        __syncthreads();
        if (t == 0) out[(size_t)N_VEC * D] = expf(-(ws[0] + ws[1] + ws[2] + ws[3]));
    }
}

// ---------------------------------------------------------------------------
extern "C" void kernel_launch(void* const* d_in, const int* in_sizes, int n_in,
                              void* d_out, int out_size, void* d_ws, size_t ws_size,
                              hipStream_t stream) {
    const float* x   = (const float*)d_in[0];   // [65536, 64] fp32
    const float* emb = (const float*)d_in[1];   // [1024, 64] fp32
    float* out = (float*)d_out;                 // 4194304 quantized + 1 perplexity

    uint4* ep     = (uint4*)d_ws;                                      // 256 KB packed
    float* enorm  = (float*)((char*)d_ws + (size_t)K * 128 * 2);       // 4 KB (-0.5*||e||^2)
    int*   counts = (int*)((char*)enorm + K * sizeof(float));          // K+1 ints

    pack_e_kernel<<<64, 64, 0, stream>>>(emb, ep, enorm, counts);
    vq_kernel<<<N_VEC / 64, 256, 0, stream>>>(x, emb, ep, enorm, counts, out);
}

// Round 5
// 154.722 us; speedup vs baseline: 1.0706x; 1.0706x over previous
//
#include <hip/hip_runtime.h>
#include <math.h>

#define N_VEC 65536
#define D 64
#define K 1024
#define VQ_EPS 1e-10f

typedef __attribute__((ext_vector_type(8))) short s16x8;   // 8 bf16 = 4 VGPR
typedef __attribute__((ext_vector_type(4))) float f32x4;   // MFMA acc

#define MFMA(a, b, c) __builtin_amdgcn_mfma_f32_16x16x32_bf16((a), (b), (c), 0, 0, 0)

__device__ __forceinline__ unsigned short bf16_rne(float f) {
    unsigned u = __float_as_uint(f);
    u += 0x7fff + ((u >> 16) & 1);
    return (unsigned short)(u >> 16);
}
__device__ __forceinline__ float bf16_f32(unsigned short h) {
    return __uint_as_float(((unsigned)h) << 16);
}

// async global->LDS DMA, 16 B per lane; LDS dest = wave-uniform base + lane*16
__device__ __forceinline__ void async_load16(const void* g, void* lds_generic) {
    __builtin_amdgcn_global_load_lds(
        (const __attribute__((address_space(1))) unsigned int*)g,
        (__attribute__((address_space(3))) unsigned int*)lds_generic, 16, 0, 0);
}

// ---------------------------------------------------------------------------
// Kernel A: pack embeddings into MFMA-fragment order (verified layout).
// Chunk id = ct*16 + g*4 + bg (bg: 0=hi k0-31, 1=hi k32-63, 2=lo k0-31,
// 3=lo k32-63). Slot q*16+c in a chunk = 16 B = 8 bf16 of code g*16+c.
// enorm stores -0.5*||e||^2; counts[K] doubles as completion counter.
// ---------------------------------------------------------------------------
__global__ void pack_e_kernel(const float* __restrict__ emb,
                              uint4* __restrict__ ep4,
                              float* __restrict__ enorm,
                              int* __restrict__ counts) {
    int gid = blockIdx.x * 64 + threadIdx.x;       // 0..4095
    int code = gid >> 2, tq = gid & 3;             // tq: k-quarter (16 elems)
    const float* row = emb + (size_t)code * D + tq * 16;
    unsigned int hi[8], lo[8];
    float nrm = 0.f;
#pragma unroll
    for (int i = 0; i < 4; ++i) {
        float4 v = *reinterpret_cast<const float4*>(row + i * 4);
        nrm += v.x * v.x + v.y * v.y + v.z * v.z + v.w * v.w;
        float f[4] = {v.x, v.y, v.z, v.w};
        unsigned short hh[4], ll[4];
#pragma unroll
        for (int j = 0; j < 4; ++j) {
            hh[j] = bf16_rne(f[j]);
            ll[j] = bf16_rne(f[j] - bf16_f32(hh[j]));
        }
        hi[i * 2 + 0] = (unsigned)hh[0] | ((unsigned)hh[1] << 16);
        hi[i * 2 + 1] = (unsigned)hh[2] | ((unsigned)hh[3] << 16);
        lo[i * 2 + 0] = (unsigned)ll[0] | ((unsigned)ll[1] << 16);
        lo[i * 2 + 1] = (unsigned)ll[2] | ((unsigned)ll[3] << 16);
    }
    const int ct = code >> 6, g = (code >> 4) & 3, c = code & 15;
#pragma unroll
    for (int h = 0; h < 2; ++h) {
        int gran = 2 * tq + h;               // 0..7
        int bg = gran >> 2, qq = gran & 3;
        ep4[(size_t)(ct * 16 + g * 4 + bg) * 64 + qq * 16 + c] =
            make_uint4(hi[h * 4], hi[h * 4 + 1], hi[h * 4 + 2], hi[h * 4 + 3]);
        int granl = 8 + gran;                // lo: bg 2..3
        bg = granl >> 2; qq = granl & 3;
        ep4[(size_t)(ct * 16 + g * 4 + bg) * 64 + qq * 16 + c] =
            make_uint4(lo[h * 4], lo[h * 4 + 1], lo[h * 4 + 2], lo[h * 4 + 3]);
    }
    nrm += __shfl_xor(nrm, 1, 64);
    nrm += __shfl_xor(nrm, 2, 64);
    if (tq == 0) enorm[code] = -0.5f * nrm;        // pre-negated half-norm
    if (gid <= K) counts[gid] = 0;                 // counts[K] = completion ctr
}

// ---------------------------------------------------------------------------
// Kernel B: EXACT R0 body (proven best: per-group 6-MFMA with e2 C-init and
// immediate per-group update — R4 proved batching regresses) with only the
// sync/traffic shape changed:
//  (1) counted-vmcnt barrier (T4): issue next tile's 4 DMAs, then
//      s_waitcnt vmcnt(4) + raw s_barrier — prefetch stays in flight across
//      the barrier; never drains to 0 in the main loop (was: __syncthreads
//      = vmcnt(0) drain x16, each paying the DMA tail latency).
//  (2) tile-phase stagger: block starts at tile (blockIdx>>3)&15 so the
//      128 blocks per XCD spread over all 16 tiles instead of convoying on
//      one 16 KB tile per window. Requires lexicographic (score,idx) update
//      (exact fp32 scores -> result identical to ascending first-occurrence).
// C-layout: col(code)=lane&15, row(vec)=(lane>>4)*4+reg (m89-verified).
// ---------------------------------------------------------------------------
__global__ void __launch_bounds__(256, 4)
vq_kernel(const float* __restrict__ x,
          const float* __restrict__ emb,
          const uint4* __restrict__ ep4,
          const float* __restrict__ enormp,   // holds -0.5*||e||^2
          int* __restrict__ counts,           // K+1 ints; [K] = completion ctr
          float* __restrict__ out) {
    __shared__ __align__(16) unsigned short bt[2][64 * 128];   // 2 x 16 KB B
    __shared__ __align__(16) float en[K];                      // 4 KB norms
    __shared__ int   bks[64];
    __shared__ float ws[4];
    __shared__ int   amLast;

    const int t    = threadIdx.x;
    const int w    = t >> 6;
    const int lane = t & 63;
    const int q    = lane >> 4;
    const int c    = lane & 15;
    const int vb   = blockIdx.x * 64;
    const int s0   = (blockIdx.x >> 3) & 15;   // stagger: uniform within XCD

    // ---- all 1024 norms -> LDS (one float4 per thread) ----
    reinterpret_cast<float4*>(en)[t] = reinterpret_cast<const float4*>(enormp)[t];

    // ---- A-frags: 16 vectors/wave, bf16 hi/lo (16 VGPR) ----
    s16x8 Ah0, Ah1, Al0, Al1;
#define LOAD_A(h, AH, AL)                                                      \
    {                                                                          \
        const float* xr = x + (size_t)(vb + w * 16 + c) * D + (h) * 32 + q * 8;\
        float4 u0 = *reinterpret_cast<const float4*>(xr);                      \
        float4 u1 = *reinterpret_cast<const float4*>(xr + 4);                  \
        float f[8] = {u0.x, u0.y, u0.z, u0.w, u1.x, u1.y, u1.z, u1.w};         \
        s16x8 hiv, lov;                                                        \
        _Pragma("unroll") for (int j = 0; j < 8; ++j) {                        \
            unsigned short hb = bf16_rne(f[j]);                                \
            hiv[j] = (short)hb;                                                \
            lov[j] = (short)bf16_rne(f[j] - bf16_f32(hb));                     \
        }                                                                      \
        AH = hiv; AL = lov;                                                    \
    }
    LOAD_A(0, Ah0, Al0)
    LOAD_A(1, Ah1, Al1)
#undef LOAD_A

    // ---- prologue: DMA tile s0's chunks (wave w -> chunks w*4..w*4+3) ----
    {
        const char* gbase = (const char*)ep4
            + (size_t)(s0 * 16 + w * 4) * 1024 + lane * 16;
        char* lbase = (char*)bt[0] + (w * 4) * 1024;
#pragma unroll
        for (int i = 0; i < 4; ++i)
            async_load16(gbase + i * 1024, lbase + i * 1024);
    }

    float best[4];
    int   bk_[4];
#pragma unroll
    for (int s = 0; s < 4; ++s) { best[s] = -3.4e38f; bk_[s] = 0; }

    // my en ds_writes must be in LDS before the first raw barrier publishes
    asm volatile("s_waitcnt lgkmcnt(0)" ::: "memory");

    for (int i = 0; i < 16; ++i) {
        const int p = (s0 + i) & 15;           // physical tile this iteration

        if (i < 15) {                          // DMA next tile, keep in flight
            const int pn = (s0 + i + 1) & 15;
            const char* gbase = (const char*)ep4
                + (size_t)(pn * 16 + w * 4) * 1024 + lane * 16;
            char* lbase = (char*)bt[(i + 1) & 1] + (w * 4) * 1024;
#pragma unroll
            for (int j = 0; j < 4; ++j)
                async_load16(gbase + j * 1024, lbase + j * 1024);
            __builtin_amdgcn_sched_barrier(0);
            asm volatile("s_waitcnt vmcnt(4)" ::: "memory");  // tile i landed;
        } else {                                              // 4 newer in flight
            asm volatile("s_waitcnt vmcnt(0)" ::: "memory");  // final tile
        }
        __builtin_amdgcn_sched_barrier(0);
        __builtin_amdgcn_s_barrier();          // raw barrier: no vmcnt(0) drain
        __builtin_amdgcn_sched_barrier(0);

        const unsigned short* bufS = bt[i & 1];
#pragma unroll
        for (int g = 0; g < 4; ++g) {
            // canonical conflict-free b128 reads: chunk*512 shorts + lane*8
            s16x8 Bh0 = *reinterpret_cast<const s16x8*>(bufS + (g * 4 + 0) * 512 + lane * 8);
            s16x8 Bh1 = *reinterpret_cast<const s16x8*>(bufS + (g * 4 + 1) * 512 + lane * 8);
            s16x8 Bl0 = *reinterpret_cast<const s16x8*>(bufS + (g * 4 + 2) * 512 + lane * 8);
            s16x8 Bl1 = *reinterpret_cast<const s16x8*>(bufS + (g * 4 + 3) * 512 + lane * 8);

            const int codeG = p * 64 + g * 16 + c;
            const float e2 = en[codeG];            // -||e||^2/2 as C operand
            f32x4 acc = (f32x4){e2, e2, e2, e2};

            acc = MFMA(Ah0, Bh0, acc);
            acc = MFMA(Ah1, Bh1, acc);
            acc = MFMA(Ah0, Bl0, acc);
            acc = MFMA(Ah1, Bl1, acc);
            acc = MFMA(Al0, Bh0, acc);
            acc = MFMA(Al1, Bh1, acc);

            // lexicographic (score, smaller idx) — scan-order independent
#pragma unroll
            for (int r = 0; r < 4; ++r) {
                bool better = (acc[r] > best[r]) ||
                              (acc[r] == best[r] && codeG < bk_[r]);
                if (better) { best[r] = acc[r]; bk_[r] = codeG; }
            }
        }
    }

    // ---- reduce over the 16 code-columns (max score; tie -> smaller idx) ----
#pragma unroll
    for (int m = 1; m <= 8; m <<= 1)
#pragma unroll
        for (int s = 0; s < 4; ++s) {
            float ob = __shfl_xor(best[s], m, 64);
            int   ok = __shfl_xor(bk_[s], m, 64);
            if (ob > best[s] || (ob == best[s] && ok < bk_[s])) {
                best[s] = ob; bk_[s] = ok;
            }
        }
    if (c == 0) {
#pragma unroll
        for (int r = 0; r < 4; ++r) {
            int lv = w * 16 + q * 4 + r;
            int kk = bk_[r];
            bks[lv] = kk;
            atomicAdd(&counts[kk], 1);
        }
    }
    __syncthreads();

    // ---- gather winning rows -> out (exact fp32) ----
    {
        int vec = t >> 2, part = t & 3;
        int kk = bks[vec];
        const float4* src = reinterpret_cast<const float4*>(emb + (size_t)kk * D) + part * 4;
        float4* dst = reinterpret_cast<float4*>(out + (size_t)(vb + vec) * D) + part * 4;
#pragma unroll
        for (int j = 0; j < 4; ++j) dst[j] = src[j];
    }

    // ---- last finishing block computes perplexity from counts ----
    __syncthreads();
    if (t == 0) {
        __threadfence();
        amLast = (atomicAdd(&counts[K], 1) == (int)gridDim.x - 1);
    }
    __syncthreads();
    if (amLast) {
        float s = 0.f;
#pragma unroll
        for (int i = 0; i < 4; ++i) {
            int cnt = __hip_atomic_load(&counts[t + i * 256], __ATOMIC_RELAXED,
                                        __HIP_MEMORY_SCOPE_AGENT);
            float p = (float)cnt * (1.0f / (float)N_VEC);
            s += p * logf(p + VQ_EPS);
        }
#pragma unroll
        for (int m = 1; m < 64; m <<= 1) s += __shfl_xor(s, m, 64);
        if (lane == 0) ws[w] = s;
        __syncthreads();
        if (t == 0) out[(size_t)N_VEC * D] = expf(-(ws[0] + ws[1] + ws[2] + ws[3]));
    }
}

// ---------------------------------------------------------------------------
extern "C" void kernel_launch(void* const* d_in, const int* in_sizes, int n_in,
                              void* d_out, int out_size, void* d_ws, size_t ws_size,
                              hipStream_t stream) {
    const float* x   = (const float*)d_in[0];   // [65536, 64] fp32
    const float* emb = (const float*)d_in[1];   // [1024, 64] fp32
    float* out = (float*)d_out;                 // 4194304 quantized + 1 perplexity

    uint4* ep     = (uint4*)d_ws;                                      // 256 KB packed
    float* enorm  = (float*)((char*)d_ws + (size_t)K * 128 * 2);       // 4 KB (-0.5*||e||^2)
    int*   counts = (int*)((char*)enorm + K * sizeof(float));          // K+1 ints

    pack_e_kernel<<<64, 64, 0, stream>>>(emb, ep, enorm, counts);
    vq_kernel<<<N_VEC / 64, 256, 0, stream>>>(x, emb, ep, enorm, counts, out);
}

// Round 6
// 154.050 us; speedup vs baseline: 1.0753x; 1.0044x over previous
//
#include <hip/hip_runtime.h>
#include <math.h>

#define N_VEC 65536
#define D 64
#define K 1024
#define VQ_EPS 1e-10f

typedef __attribute__((ext_vector_type(8))) short s16x8;   // 8 bf16 = 4 VGPR
typedef __attribute__((ext_vector_type(4))) float f32x4;   // MFMA acc

#define MFMA(a, b, c) __builtin_amdgcn_mfma_f32_16x16x32_bf16((a), (b), (c), 0, 0, 0)

__device__ __forceinline__ unsigned short bf16_rne(float f) {
    unsigned u = __float_as_uint(f);
    u += 0x7fff + ((u >> 16) & 1);
    return (unsigned short)(u >> 16);
}
__device__ __forceinline__ float bf16_f32(unsigned short h) {
    return __uint_as_float(((unsigned)h) << 16);
}

// async global->LDS DMA, 16 B per lane; LDS dest = wave-uniform base + lane*16
__device__ __forceinline__ void async_load16(const void* g, void* lds_generic) {
    __builtin_amdgcn_global_load_lds(
        (const __attribute__((address_space(1))) unsigned int*)g,
        (__attribute__((address_space(3))) unsigned int*)lds_generic, 16, 0, 0);
}

// ---------------------------------------------------------------------------
// Kernel A: pack embeddings into MFMA-fragment order (verified layout).
// Chunk id = ct*16 + g*4 + bg (bg: 0=hi k0-31, 1=hi k32-63, 2=lo k0-31,
// 3=lo k32-63). Slot q*16+c in a chunk = 16 B = 8 bf16 of code g*16+c.
// enorm stores -0.5*||e||^2; counts[K] doubles as completion counter.
// ---------------------------------------------------------------------------
__global__ void pack_e_kernel(const float* __restrict__ emb,
                              uint4* __restrict__ ep4,
                              float* __restrict__ enorm,
                              int* __restrict__ counts) {
    int gid = blockIdx.x * 64 + threadIdx.x;       // 0..4095
    int code = gid >> 2, tq = gid & 3;             // tq: k-quarter (16 elems)
    const float* row = emb + (size_t)code * D + tq * 16;
    unsigned int hi[8], lo[8];
    float nrm = 0.f;
#pragma unroll
    for (int i = 0; i < 4; ++i) {
        float4 v = *reinterpret_cast<const float4*>(row + i * 4);
        nrm += v.x * v.x + v.y * v.y + v.z * v.z + v.w * v.w;
        float f[4] = {v.x, v.y, v.z, v.w};
        unsigned short hh[4], ll[4];
#pragma unroll
        for (int j = 0; j < 4; ++j) {
            hh[j] = bf16_rne(f[j]);
            ll[j] = bf16_rne(f[j] - bf16_f32(hh[j]));
        }
        hi[i * 2 + 0] = (unsigned)hh[0] | ((unsigned)hh[1] << 16);
        hi[i * 2 + 1] = (unsigned)hh[2] | ((unsigned)hh[3] << 16);
        lo[i * 2 + 0] = (unsigned)ll[0] | ((unsigned)ll[1] << 16);
        lo[i * 2 + 1] = (unsigned)ll[2] | ((unsigned)ll[3] << 16);
    }
    const int ct = code >> 6, g = (code >> 4) & 3, c = code & 15;
#pragma unroll
    for (int h = 0; h < 2; ++h) {
        int gran = 2 * tq + h;               // 0..7
        int bg = gran >> 2, qq = gran & 3;
        ep4[(size_t)(ct * 16 + g * 4 + bg) * 64 + qq * 16 + c] =
            make_uint4(hi[h * 4], hi[h * 4 + 1], hi[h * 4 + 2], hi[h * 4 + 3]);
        int granl = 8 + gran;                // lo: bg 2..3
        bg = granl >> 2; qq = granl & 3;
        ep4[(size_t)(ct * 16 + g * 4 + bg) * 64 + qq * 16 + c] =
            make_uint4(lo[h * 4], lo[h * 4 + 1], lo[h * 4 + 2], lo[h * 4 + 3]);
    }
    nrm += __shfl_xor(nrm, 1, 64);
    nrm += __shfl_xor(nrm, 2, 64);
    if (tq == 0) enorm[code] = -0.5f * nrm;        // pre-negated half-norm
    if (gid <= K) counts[gid] = 0;                 // counts[K] = completion ctr
}

// ---------------------------------------------------------------------------
// Kernel B: EXACT R0 structure (best measured: 4 blocks/CU, 16 waves/CU,
// 16 KB dbuf tiles, __syncthreads per tile, per-group 6-MFMA with e2 C-init
// and immediate per-group update). Single variable vs R0: TILE-PHASE STAGGER
// — block starts its codebook sweep at tile (blockIdx>>3)&15, spreading each
// phase window's L2 demand over all 16 tiles instead of convoying on one.
// Race-free: barrier -> DMA-next -> compute order is unchanged from R0.
// Update is lexicographic (score, smaller idx): scan-order independent,
// identical winners to ascending first-occurrence.
// C-layout: col(code)=lane&15, row(vec)=(lane>>4)*4+reg (m89-verified).
// ---------------------------------------------------------------------------
__global__ void __launch_bounds__(256, 4)
vq_kernel(const float* __restrict__ x,
          const float* __restrict__ emb,
          const uint4* __restrict__ ep4,
          const float* __restrict__ enormp,   // holds -0.5*||e||^2
          int* __restrict__ counts,           // K+1 ints; [K] = completion ctr
          float* __restrict__ out) {
    __shared__ __align__(16) unsigned short bt[2][64 * 128];   // 2 x 16 KB B
    __shared__ __align__(16) float en[K];                      // 4 KB norms
    __shared__ int   bks[64];
    __shared__ float ws[4];
    __shared__ int   amLast;

    const int t    = threadIdx.x;
    const int w    = t >> 6;
    const int lane = t & 63;
    const int q    = lane >> 4;
    const int c    = lane & 15;
    const int vb   = blockIdx.x * 64;
    const int s0   = (blockIdx.x >> 3) & 15;   // stagger: uniform within XCD

    // ---- all 1024 norms -> LDS (one float4 per thread) ----
    reinterpret_cast<float4*>(en)[t] = reinterpret_cast<const float4*>(enormp)[t];

    // ---- A-frags: 16 vectors/wave, bf16 hi/lo (16 VGPR) ----
    s16x8 Ah0, Ah1, Al0, Al1;
#define LOAD_A(h, AH, AL)                                                      \
    {                                                                          \
        const float* xr = x + (size_t)(vb + w * 16 + c) * D + (h) * 32 + q * 8;\
        float4 u0 = *reinterpret_cast<const float4*>(xr);                      \
        float4 u1 = *reinterpret_cast<const float4*>(xr + 4);                  \
        float f[8] = {u0.x, u0.y, u0.z, u0.w, u1.x, u1.y, u1.z, u1.w};         \
        s16x8 hiv, lov;                                                        \
        _Pragma("unroll") for (int j = 0; j < 8; ++j) {                        \
            unsigned short hb = bf16_rne(f[j]);                                \
            hiv[j] = (short)hb;                                                \
            lov[j] = (short)bf16_rne(f[j] - bf16_f32(hb));                     \
        }                                                                      \
        AH = hiv; AL = lov;                                                    \
    }
    LOAD_A(0, Ah0, Al0)
    LOAD_A(1, Ah1, Al1)
#undef LOAD_A

    // ---- prologue: DMA tile s0's chunks (wave w -> chunks w*4..w*4+3) ----
    {
        const char* gbase = (const char*)ep4
            + (size_t)(s0 * 16 + w * 4) * 1024 + lane * 16;
        char* lbase = (char*)bt[0] + (w * 4) * 1024;
#pragma unroll
        for (int i = 0; i < 4; ++i)
            async_load16(gbase + i * 1024, lbase + i * 1024);
    }

    float best[4];
    int   bk_[4];
#pragma unroll
    for (int s = 0; s < 4; ++s) { best[s] = -3.4e38f; bk_[s] = 0; }

#pragma unroll 1
    for (int i = 0; i < 16; ++i) {
        const int p = (s0 + i) & 15;   // physical tile this iteration

        __syncthreads();   // vmcnt(0)+barrier: tile i ready in bt[i&1];
                           // everyone done reading bt[(i+1)&1]

        if (i < 15) {      // DMA next tile into the other buffer
            const int pn = (s0 + i + 1) & 15;
            const char* gbase = (const char*)ep4
                + (size_t)(pn * 16 + w * 4) * 1024 + lane * 16;
            char* lbase = (char*)bt[(i + 1) & 1] + (w * 4) * 1024;
#pragma unroll
            for (int j = 0; j < 4; ++j)
                async_load16(gbase + j * 1024, lbase + j * 1024);
        }

        const unsigned short* bufS = bt[i & 1];
#pragma unroll
        for (int g = 0; g < 4; ++g) {
            // canonical conflict-free b128 reads: chunk*512 shorts + lane*8
            s16x8 Bh0 = *reinterpret_cast<const s16x8*>(bufS + (g * 4 + 0) * 512 + lane * 8);
            s16x8 Bh1 = *reinterpret_cast<const s16x8*>(bufS + (g * 4 + 1) * 512 + lane * 8);
            s16x8 Bl0 = *reinterpret_cast<const s16x8*>(bufS + (g * 4 + 2) * 512 + lane * 8);
            s16x8 Bl1 = *reinterpret_cast<const s16x8*>(bufS + (g * 4 + 3) * 512 + lane * 8);

            const int codeG = p * 64 + g * 16 + c;
            const float e2 = en[codeG];            // -||e||^2/2 as C operand
            f32x4 acc = (f32x4){e2, e2, e2, e2};

            acc = MFMA(Ah0, Bh0, acc);
            acc = MFMA(Ah1, Bh1, acc);
            acc = MFMA(Ah0, Bl0, acc);
            acc = MFMA(Ah1, Bl1, acc);
            acc = MFMA(Al0, Bh0, acc);
            acc = MFMA(Al1, Bh1, acc);

            // lexicographic (score, smaller idx) — scan-order independent
#pragma unroll
            for (int r = 0; r < 4; ++r) {
                bool better = (acc[r] > best[r]) ||
                              (acc[r] == best[r] && codeG < bk_[r]);
                if (better) { best[r] = acc[r]; bk_[r] = codeG; }
            }
        }
    }

    // ---- reduce over the 16 code-columns (max score; tie -> smaller idx) ----
#pragma unroll
    for (int m = 1; m <= 8; m <<= 1)
#pragma unroll
        for (int s = 0; s < 4; ++s) {
            float ob = __shfl_xor(best[s], m, 64);
            int   ok = __shfl_xor(bk_[s], m, 64);
            if (ob > best[s] || (ob == best[s] && ok < bk_[s])) {
                best[s] = ob; bk_[s] = ok;
            }
        }
    if (c == 0) {
#pragma unroll
        for (int r = 0; r < 4; ++r) {
            int lv = w * 16 + q * 4 + r;
            int kk = bk_[r];
            bks[lv] = kk;
            atomicAdd(&counts[kk], 1);
        }
    }
    __syncthreads();

    // ---- gather winning rows -> out (exact fp32) ----
    {
        int vec = t >> 2, part = t & 3;
        int kk = bks[vec];
        const float4* src = reinterpret_cast<const float4*>(emb + (size_t)kk * D) + part * 4;
        float4* dst = reinterpret_cast<float4*>(out + (size_t)(vb + vec) * D) + part * 4;
#pragma unroll
        for (int j = 0; j < 4; ++j) dst[j] = src[j];
    }

    // ---- last finishing block computes perplexity from counts ----
    __syncthreads();
    if (t == 0) {
        __threadfence();
        amLast = (atomicAdd(&counts[K], 1) == (int)gridDim.x - 1);
    }
    __syncthreads();
    if (amLast) {
        float s = 0.f;
#pragma unroll
        for (int i = 0; i < 4; ++i) {
            int cnt = __hip_atomic_load(&counts[t + i * 256], __ATOMIC_RELAXED,
                                        __HIP_MEMORY_SCOPE_AGENT);
            float p = (float)cnt * (1.0f / (float)N_VEC);
            s += p * logf(p + VQ_EPS);
        }
#pragma unroll
        for (int m = 1; m < 64; m <<= 1) s += __shfl_xor(s, m, 64);
        if (lane == 0) ws[w] = s;
        __syncthreads();
        if (t == 0) out[(size_t)N_VEC * D] = expf(-(ws[0] + ws[1] + ws[2] + ws[3]));
    }
}

// ---------------------------------------------------------------------------
extern "C" void kernel_launch(void* const* d_in, const int* in_sizes, int n_in,
                              void* d_out, int out_size, void* d_ws, size_t ws_size,
                              hipStream_t stream) {
    const float* x   = (const float*)d_in[0];   // [65536, 64] fp32
    const float* emb = (const float*)d_in[1];   // [1024, 64] fp32
    float* out = (float*)d_out;                 // 4194304 quantized + 1 perplexity

    uint4* ep     = (uint4*)d_ws;                                      // 256 KB packed
    float* enorm  = (float*)((char*)d_ws + (size_t)K * 128 * 2);       // 4 KB (-0.5*||e||^2)
    int*   counts = (int*)((char*)enorm + K * sizeof(float));          // K+1 ints

    pack_e_kernel<<<64, 64, 0, stream>>>(emb, ep, enorm, counts);
    vq_kernel<<<N_VEC / 64, 256, 0, stream>>>(x, emb, ep, enorm, counts, out);
}